// Round 4
// baseline (449.117 us; speedup 1.0000x reference)
//
#include <hip/hip_runtime.h>

typedef unsigned int u32;

#define NPIX 110592            // 48^3
#define NTILES 1728            // NPIX / 64, per batch
#define K1_BLOCKS 1728         // grid for K1 (each does 2 tiles, b-aligned)
#define K1_TPB 2
#define PART_STRIDE 4224       // 4*32*32 ctx + 128 rowsum

// ws layout (float offsets)
#define WS_WT    0                       // 64*384 transposed w_qkv
#define WS_CTX   24576                   // 2*4*32*32
#define WS_RS    32768                   // 2*128
#define WS_AT    33024                   // 2*128*64  (A transposed: [hc][o])
#define WS_PART  49408                   // partials

// kv LDS (bf16): [pix][256 cols], 16B-granule XOR swizzle (col in bf16 units)
#define KCOL(row, col) ((col) ^ (((row) & 7) << 3))

__device__ __forceinline__ void gll16(const float* g, float* l) {
    typedef const __attribute__((address_space(1))) unsigned int* gp_t;
    typedef __attribute__((address_space(3))) unsigned int* lp_t;
    __builtin_amdgcn_global_load_lds((gp_t)g, (lp_t)l, 16, 0, 0);
}
__device__ __forceinline__ u32 f2bf(float f) {           // RNE f32->bf16
    u32 u = __float_as_uint(f);
    return (u + 0x7FFFu + ((u >> 16) & 1u)) >> 16;
}
__device__ __forceinline__ float bfl(u32 u) { return __uint_as_float(u << 16); }
__device__ __forceinline__ float bfh(u32 u) { return __uint_as_float(u & 0xFFFF0000u); }

// ---------------- K0: transpose w_qkv (384x64 -> 64x384) -----------------
__global__ void k0_wt(const float* __restrict__ w, float* __restrict__ wT) {
    int idx = blockIdx.x * 256 + threadIdx.x;
    if (idx < 384 * 64) {
        int r = idx >> 6, c = idx & 63;
        wT[c * 384 + r] = w[idx];
    }
}

// ---------------- K1: k,v GEMM + ctx/rowsum accumulation -----------------
// 256 thr / 4 waves. Wave og: stages 16 x-rows, computes qkv rows
// 128+og*64..+64 (phase1), owns head h=og (phase2). lane p = pixel in tile.
// launch_bounds(256,2): VGPR cap 256 -> no spill (R3's (256,3) forced a
// VGPR=84 allocation that spilled xr[64] -> 80 MB scratch writes).
__global__ __launch_bounds__(256, 2)
void k1_ctx(const float* __restrict__ x, const float* __restrict__ wT,
            float* __restrict__ part, int usePart, int R) {
    __shared__ float xt[64 * 64];        // [c][p] f32, 16 KB
    __shared__ u32   kv[64 * 128];       // [pix][256 bf16], swizzled, 32 KB
    const int blk = blockIdx.x;
    const int p   = threadIdx.x & 63;
    const int og  = __builtin_amdgcn_readfirstlane(threadIdx.x >> 6);
    const int b   = blk / (K1_BLOCKS / 2);
    const int h   = og;
    const int c0  = (p >> 3) << 2;
    const int d0  = (p & 7) << 2;
    const float* xb = x + (long)b * 64 * NPIX;
    const int srow = (p >> 4);
    const int scol = (p & 15) << 2;

    float cc[16];
    #pragma unroll
    for (int i = 0; i < 16; ++i) cc[i] = 0.f;
    float rs[4] = {0.f, 0.f, 0.f, 0.f};

    {   // prologue: stage tile 0
        const long i0 = (long)(blk * K1_TPB - b * NTILES) * 64;
        #pragma unroll
        for (int i = 0; i < 4; ++i) {
            const int r0 = og * 16 + i * 4;
            gll16(xb + (long)(r0 + srow) * NPIX + i0 + scol, &xt[r0 * 64]);
        }
    }

    #pragma unroll 1
    for (int tt = 0; tt < K1_TPB; ++tt) {
        asm volatile("s_waitcnt vmcnt(0)" ::: "memory");
        __syncthreads();                           // x[tt] staged by all waves
        float xr[64];
        #pragma unroll
        for (int c = 0; c < 64; ++c) xr[c] = xt[c * 64 + p];
        __syncthreads();                           // all waves read x
        if (tt + 1 < K1_TPB) {                     // prefetch next tile's x
            const long i0 = (long)(blk * K1_TPB + tt + 1 - b * NTILES) * 64;
            #pragma unroll
            for (int i = 0; i < 4; ++i) {
                const int r0 = og * 16 + i * 4;
                gll16(xb + (long)(r0 + srow) * NPIX + i0 + scol, &xt[r0 * 64]);
            }
        }

        // phase 1: qkv rows 128 + og*64 .. +64, 4 chunks of 16
        const bool isK = og < 2;
        #pragma unroll 1
        for (int chunk = 0; chunk < 4; ++chunk) {
            const int o0 = og * 64 + chunk * 16;
            float acc[16];
            #pragma unroll
            for (int j = 0; j < 16; ++j) acc[j] = 0.f;
            #pragma unroll
            for (int c = 0; c < 64; ++c) {
                const float* wr = wT + c * 384 + 128 + o0;   // uniform -> s_load
                const float xv = xr[c];
                #pragma unroll
                for (int j = 0; j < 16; ++j) acc[j] = fmaf(wr[j], xv, acc[j]);
            }
            #pragma unroll
            for (int j = 0; j < 16; ++j)
                if (isK) acc[j] = __expf(acc[j]);
            u32 pk[8];
            #pragma unroll
            for (int j = 0; j < 8; ++j)
                pk[j] = f2bf(acc[2 * j]) | (f2bf(acc[2 * j + 1]) << 16);
            const int g0 = (p * 256 + KCOL(p, o0)) >> 1;       // u32 idx, 16B-al
            const int g1 = (p * 256 + KCOL(p, o0 + 8)) >> 1;
            *(uint4*)&kv[g0] = make_uint4(pk[0], pk[1], pk[2], pk[3]);
            *(uint4*)&kv[g1] = make_uint4(pk[4], pk[5], pk[6], pk[7]);
        }
        __syncthreads();                           // kv ready

        // phase 2: ctx[c0..+4][d0..+4] += ek * v over 64 pixels
        #pragma unroll 4
        for (int q = 0; q < 64; ++q) {
            const uint2 eu = *(const uint2*)&kv[(q * 256 + KCOL(q, h * 32 + c0)) >> 1];
            const uint2 vu = *(const uint2*)&kv[(q * 256 + KCOL(q, 128 + h * 32 + d0)) >> 1];
            const float ek[4] = { bfl(eu.x), bfh(eu.x), bfl(eu.y), bfh(eu.y) };
            const float vv[4] = { bfl(vu.x), bfh(vu.x), bfl(vu.y), bfh(vu.y) };
            #pragma unroll
            for (int a = 0; a < 4; ++a)
                #pragma unroll
                for (int e = 0; e < 4; ++e)
                    cc[a * 4 + e] = fmaf(ek[a], vv[e], cc[a * 4 + e]);
            #pragma unroll
            for (int a = 0; a < 4; ++a) rs[a] += ek[a];
        }
    }

    // epilogue: write per-block partial, or atomic into replicas
    if (usePart) {
        float* pp = part + (long)blk * PART_STRIDE;
        #pragma unroll
        for (int a = 0; a < 4; ++a)
            #pragma unroll
            for (int e = 0; e < 4; ++e)
                pp[h * 1024 + (c0 + a) * 32 + d0 + e] = cc[a * 4 + e];
        if (d0 == 0) {
            #pragma unroll
            for (int a = 0; a < 4; ++a) pp[4096 + h * 32 + c0 + a] = rs[a];
        }
    } else {
        float* pp = part + (long)(b * R + (blk % R)) * PART_STRIDE;
        #pragma unroll
        for (int a = 0; a < 4; ++a)
            #pragma unroll
            for (int e = 0; e < 4; ++e)
                atomicAdd(&pp[h * 1024 + (c0 + a) * 32 + d0 + e], cc[a * 4 + e]);
        if (d0 == 0) {
            #pragma unroll
            for (int a = 0; a < 4; ++a) atomicAdd(&pp[4096 + h * 32 + c0 + a], rs[a]);
        }
    }
}

// ---------------- K1b: reduce partials -> ctxU, rsum (atomic, sliced) ----
__global__ __launch_bounds__(128)
void k1b_reduce(float* __restrict__ ws, int PB) {
    const int S = 8;
    const int chunk = blockIdx.x % 33;
    const int rem   = blockIdx.x / 33;
    const int b     = rem & 1;
    const int slice = rem >> 1;
    const int j = chunk * 128 + threadIdx.x;       // [0, 4224)
    const int PBh = PB >> 1;
    const int range = PBh / S;
    const float* part = ws + WS_PART;
    float s = 0.f;
    const long base = ((long)b * PBh + (long)slice * range) * PART_STRIDE + j;
    for (int i = 0; i < range; ++i) s += part[base + (long)i * PART_STRIDE];
    float* dst = (j < 4096) ? (ws + WS_CTX + b * 4096 + j)
                            : (ws + WS_RS + b * 128 + (j - 4096));
    atomicAdd(dst, s);
}

// ---------------- K2: A_T[hc][o] = sum_d w_out[o,hd]*ctx[h][c][d]/rsum ---
__global__ __launch_bounds__(256)
void k2_prepA(const float* __restrict__ wout, float* __restrict__ ws) {
    __shared__ float wo[64 * 129];
    __shared__ float ct[4096];
    __shared__ float rsum[128];
    const int b  = blockIdx.x >> 3;
    const int jb = blockIdx.x & 7;
    const int tid = threadIdx.x;
    for (int i = tid; i < 8192; i += 256) wo[(i >> 7) * 129 + (i & 127)] = wout[i];
    for (int i = tid; i < 4096; i += 256) ct[i] = ws[WS_CTX + b * 4096 + i];
    if (tid < 128) rsum[tid] = ws[WS_RS + b * 128 + tid];
    __syncthreads();
    float* AT = ws + WS_AT + b * 8192;
    for (int j = jb * 4; j < jb * 4 + 4; ++j) {
        const int m  = j * 256 + tid;
        const int hc = m >> 6;
        const int o  = m & 63;
        const int hh = hc >> 5, c = hc & 31;
        float s = 0.f;
        #pragma unroll
        for (int d = 0; d < 32; ++d)
            s = fmaf(wo[o * 129 + hh * 32 + d], ct[hh * 1024 + c * 32 + d], s);
        AT[hc * 64 + o] = s / rsum[hc];
    }
}

// ---------------- K3: q GEMM + in-reg softmax + A@q + bias ---------------
// Wave og computes its own head's 32 q-rows in registers (chunk loop fully
// unrolled -> static qv indices), softmaxes in-reg, writes only softmax'd q
// as packed bf16 (16 KB). LDS total 32 KB -> 5 blocks/CU.
__global__ __launch_bounds__(256, 2)
void k3_out(const float* __restrict__ x, const float* __restrict__ wT,
            const float* __restrict__ bout, const float* __restrict__ ws,
            float* __restrict__ out) {
    __shared__ float xt[64 * 64];        // staged x tile, 16 KB
    __shared__ u32   qlb[64 * 64];       // [row-pair][px] packed bf16, 16 KB
    const int  blk  = blockIdx.x;
    const int  b    = blk / NTILES;
    const int  tile = blk % NTILES;
    const long i0   = (long)tile * 64;
    const int  p  = threadIdx.x & 63;
    const int  og = __builtin_amdgcn_readfirstlane(threadIdx.x >> 6);
    const float* xb = x + (long)b * 64 * NPIX;
    const int srow = (p >> 4);
    const int scol = (p & 15) << 2;

    #pragma unroll
    for (int i = 0; i < 4; ++i) {
        const int r0 = og * 16 + i * 4;
        gll16(xb + (long)(r0 + srow) * NPIX + i0 + scol, &xt[r0 * 64]);
    }
    asm volatile("s_waitcnt vmcnt(0)" ::: "memory");
    __syncthreads();
    float xr[64];
    #pragma unroll
    for (int c = 0; c < 64; ++c) xr[c] = xt[c * 64 + p];

    // phase 1: q rows og*32..+32 in registers (2 chunks of 16, unrolled)
    float qv[32];
    #pragma unroll
    for (int chunk = 0; chunk < 2; ++chunk) {
        const int o0 = og * 32 + chunk * 16;
        float acc[16];
        #pragma unroll
        for (int j = 0; j < 16; ++j) acc[j] = 0.f;
        #pragma unroll
        for (int c = 0; c < 64; ++c) {
            const float* wr = wT + c * 384 + o0;           // uniform -> s_load
            const float xv = xr[c];
            #pragma unroll
            for (int j = 0; j < 16; ++j) acc[j] = fmaf(wr[j], xv, acc[j]);
        }
        #pragma unroll
        for (int j = 0; j < 16; ++j) qv[chunk * 16 + j] = acc[j];
    }

    // phase 2: in-register softmax over head og's 32 dims, column p
    {
        float m = qv[0];
        #pragma unroll
        for (int c = 1; c < 32; ++c) m = fmaxf(m, qv[c]);
        float s = 0.f;
        #pragma unroll
        for (int c = 0; c < 32; ++c) { qv[c] = __expf(qv[c] - m); s += qv[c]; }
        const float inv = 1.0f / s;
        #pragma unroll
        for (int c2 = 0; c2 < 16; ++c2)
            qlb[(og * 16 + c2) * 64 + p] =
                f2bf(qv[2 * c2] * inv) | (f2bf(qv[2 * c2 + 1] * inv) << 16);
    }
    __syncthreads();

    // phase 3: out[o0..+16][p] = b_out + sum_hc A_T[hc][o] * qsm[hc][p]
    {
        const int o0 = og * 16;
        const float* AT = ws + WS_AT + b * 8192;
        float acc[16];
        #pragma unroll
        for (int j = 0; j < 16; ++j) acc[j] = bout[o0 + j];
        #pragma unroll 2
        for (int rp = 0; rp < 64; ++rp) {
            const u32 uq = qlb[rp * 64 + p];
            const float q0 = bfl(uq), q1 = bfh(uq);
            const float* a0 = AT + (2 * rp) * 64 + o0;     // uniform -> s_load
            const float* a1 = AT + (2 * rp + 1) * 64 + o0;
            #pragma unroll
            for (int j = 0; j < 16; ++j) acc[j] = fmaf(a0[j], q0, acc[j]);
            #pragma unroll
            for (int j = 0; j < 16; ++j) acc[j] = fmaf(a1[j], q1, acc[j]);
        }
        float* op = out + ((long)b * 64 + o0) * NPIX + i0 + p;
        #pragma unroll
        for (int j = 0; j < 16; ++j) op[(long)j * NPIX] = acc[j];
    }
}

extern "C" void kernel_launch(void* const* d_in, const int* in_sizes, int n_in,
                              void* d_out, int out_size, void* d_ws, size_t ws_size,
                              hipStream_t stream) {
    (void)in_sizes; (void)n_in; (void)out_size;
    const float* x     = (const float*)d_in[0];
    const float* w_qkv = (const float*)d_in[1];
    const float* w_out = (const float*)d_in[2];
    const float* b_out = (const float*)d_in[3];
    float* out = (float*)d_out;
    float* ws  = (float*)d_ws;

    const size_t need_part = ((size_t)WS_PART + (size_t)K1_BLOCKS * PART_STRIDE) * 4;
    const int usePart = (ws_size >= need_part) ? 1 : 0;
    int R = 8;
    const size_t need_r8 = ((size_t)WS_PART + (size_t)2 * 8 * PART_STRIDE) * 4;
    if (!usePart && ws_size < need_r8) R = 1;
    const int PB = usePart ? K1_BLOCKS : 2 * R;
    float* part = ws + WS_PART;

    hipLaunchKernelGGL(k0_wt, dim3(96), dim3(256), 0, stream, w_qkv, ws + WS_WT);
    if (!usePart)
        hipMemsetAsync(part, 0, (size_t)PB * PART_STRIDE * 4, stream);
    hipLaunchKernelGGL(k1_ctx, dim3(K1_BLOCKS), dim3(256), 0, stream,
                       x, ws + WS_WT, part, usePart, R);
    hipMemsetAsync(ws + WS_CTX, 0, (size_t)(2 * PART_STRIDE) * 4, stream);
    hipLaunchKernelGGL(k1b_reduce, dim3(528), dim3(128), 0, stream, ws, PB);
    hipLaunchKernelGGL(k2_prepA, dim3(16), dim3(256), 0, stream, w_out, ws);
    hipLaunchKernelGGL(k3_out, dim3(2 * NTILES), dim3(256), 0, stream,
                       x, ws + WS_WT, b_out, ws, out);
}

// Round 5
// 124.632 us; speedup vs baseline: 3.6035x; 3.6035x over previous
//
#include <hip/hip_runtime.h>

typedef unsigned int u32;
typedef unsigned short u16;
typedef __attribute__((ext_vector_type(8))) short bf16x8;   // 8 bf16 in 4 VGPRs
typedef __attribute__((ext_vector_type(4))) float f32x4;

#define NPIX 110592            // 48^3
#define NTILES 1728            // NPIX/64 per batch
#define K1_BLOCKS 1728         // each block: 2 tiles, b-aligned
#define K1_TPB 2
#define PART_STRIDE 4224       // 4096 ctx + 128 rowsum

// ws layout (4-byte slots)
#define WS_CTX   0             // 2*4096 f32
#define WS_RS    8192          // 2*128 f32
#define WS_ATB   8448          // 2*4096 u32 (packed bf16 pairs of A^T)
#define WS_PART  16640

union FragU { u32 u[4]; bf16x8 v; };

#define MFMA(a,b,c) __builtin_amdgcn_mfma_f32_16x16x32_bf16((a),(b),(c),0,0,0)

__device__ __forceinline__ void gll16(const float* g, float* l) {
    typedef const __attribute__((address_space(1))) unsigned int* gp_t;
    typedef __attribute__((address_space(3))) unsigned int* lp_t;
    __builtin_amdgcn_global_load_lds((gp_t)g, (lp_t)l, 16, 0, 0);
}
__device__ __forceinline__ u32 f2bf(float f) {            // RNE f32->bf16 bits
    u32 u = __float_as_uint(f);
    return (u + 0x7FFFu + ((u >> 16) & 1u)) >> 16;
}
__device__ __forceinline__ float bf2f(u32 bits) { return __uint_as_float(bits << 16); }
__device__ __forceinline__ u32 pk2(float a, float b) { return f2bf(a) | (f2bf(b) << 16); }
__device__ __forceinline__ void split2(float a, float b, u32& hi, u32& lo) {
    u32 ha = f2bf(a), hb = f2bf(b);
    hi = ha | (hb << 16);
    lo = pk2(a - bf2f(ha), b - bf2f(hb));
}

// ---------------- K1: k,v GEMM (MFMA) + ctx/rowsum (MFMA) ----------------
// 256 thr / 4 waves. Wave og: phase1 computes qkv rows 128+og*64..+64 into
// kvb (bf16); phase2 head h=og: ctx += EK(32xK) x V^T(Kx32), rowsum via
// B=ones. x staged f32 via global_load_lds, transpose-packed to split bf16.
__global__ __launch_bounds__(256, 2)
void k1_ctx(const float* __restrict__ x, const float* __restrict__ wq,
            float* __restrict__ part, int usePart, int R) {
    __shared__ float xt[64 * 64];      // [c][px] f32, 16 KB
    __shared__ u32   xbh[64 * 32];     // [px][cpair hi], swizzled, 8 KB
    __shared__ u32   xbl[64 * 32];     // [px][cpair lo], 8 KB
    __shared__ u32   kvb[256 * 32];    // [row][px-pair] bf16, swizzled, 32 KB
    const int blk = blockIdx.x;
    const int p   = threadIdx.x & 63;
    const int og  = __builtin_amdgcn_readfirstlane(threadIdx.x >> 6);
    const int b   = blk / (K1_BLOCKS / 2);
    const int q   = p >> 4;
    const int l15 = p & 15;
    const int yv  = (p & 7) << 2;
    const float* xg = x + (long)b * 64 * NPIX;
    const int srow = p >> 4, scol = (p & 15) << 2;

    // W fragments (rows 128 + og*64 ..+64), split hi/lo, resident in VGPRs
    FragU wh[4][2], wl[4][2];
    #pragma unroll
    for (int mi = 0; mi < 4; ++mi)
        #pragma unroll
        for (int ks = 0; ks < 2; ++ks) {
            const int row = 128 + og * 64 + mi * 16 + l15;
            const float* wp = wq + row * 64 + ks * 32 + q * 4;
            float4 f0 = *(const float4*)wp;
            float4 f1 = *(const float4*)(wp + 16);
            split2(f0.x, f0.y, wh[mi][ks].u[0], wl[mi][ks].u[0]);
            split2(f0.z, f0.w, wh[mi][ks].u[1], wl[mi][ks].u[1]);
            split2(f1.x, f1.y, wh[mi][ks].u[2], wl[mi][ks].u[2]);
            split2(f1.z, f1.w, wh[mi][ks].u[3], wl[mi][ks].u[3]);
        }

    FragU ones;
    #pragma unroll
    for (int i = 0; i < 4; ++i) ones.u[i] = 0x3F803F80u;

    f32x4 cc[2][2], rsa[2];
    #pragma unroll
    for (int mi = 0; mi < 2; ++mi) {
        #pragma unroll
        for (int ni = 0; ni < 2; ++ni) cc[mi][ni] = (f32x4)0.f;
        rsa[mi] = (f32x4)0.f;
    }

    {   // prologue: stage tile 0
        const long i0 = (long)(blk * K1_TPB - b * NTILES) * 64;
        #pragma unroll
        for (int i = 0; i < 4; ++i) {
            const int r0 = og * 16 + i * 4;
            gll16(xg + (long)(r0 + srow) * NPIX + i0 + scol, &xt[r0 * 64]);
        }
    }

    #pragma unroll 1
    for (int tt = 0; tt < K1_TPB; ++tt) {
        asm volatile("s_waitcnt vmcnt(0)" ::: "memory");
        __syncthreads();                         // xt staged; prev phase2 done

        // transpose-pack xt -> split bf16 xbh/xbl
        {
            const int px = threadIdx.x & 63;
            const int cg = threadIdx.x >> 6;     // 0..3
            u32 hb_[8], lb_[8];
            #pragma unroll
            for (int w = 0; w < 8; ++w) {
                const int c = (cg * 8 + w) * 2;
                split2(xt[c * 64 + px], xt[(c + 1) * 64 + px], hb_[w], lb_[w]);
            }
            const int yy = (px & 7) << 2;
            const int sA = (cg * 8) ^ yy;
            const int sB = (cg * 8 + 4) ^ yy;
            *(uint4*)&xbh[px * 32 + sA] = make_uint4(hb_[0], hb_[1], hb_[2], hb_[3]);
            *(uint4*)&xbh[px * 32 + sB] = make_uint4(hb_[4], hb_[5], hb_[6], hb_[7]);
            *(uint4*)&xbl[px * 32 + sA] = make_uint4(lb_[0], lb_[1], lb_[2], lb_[3]);
            *(uint4*)&xbl[px * 32 + sB] = make_uint4(lb_[4], lb_[5], lb_[6], lb_[7]);
        }
        __syncthreads();                         // xb ready, xt consumed

        if (tt + 1 < K1_TPB) {                   // prefetch next tile's x
            const long i0 = (long)(blk * K1_TPB + tt + 1 - b * NTILES) * 64;
            #pragma unroll
            for (int i = 0; i < 4; ++i) {
                const int r0 = og * 16 + i * 4;
                gll16(xg + (long)(r0 + srow) * NPIX + i0 + scol, &xt[r0 * 64]);
            }
        }

        // phase 1: D[o][px] = W x, split-bf16 (3 mfma per term)
        f32x4 a1[4][4];
        #pragma unroll
        for (int mi = 0; mi < 4; ++mi)
            #pragma unroll
            for (int ni = 0; ni < 4; ++ni) a1[mi][ni] = (f32x4)0.f;
        #pragma unroll
        for (int ni = 0; ni < 4; ++ni) {
            const int rb = (ni * 16 + l15) * 32;
            FragU bh[2], bl[2];
            #pragma unroll
            for (int ks = 0; ks < 2; ++ks) {
                const int c0 = (ks * 16 + 2 * q) ^ yv;
                const int c1 = (ks * 16 + 2 * q + 8) ^ yv;
                uint2 t0 = *(const uint2*)&xbh[rb + c0];
                uint2 t1 = *(const uint2*)&xbh[rb + c1];
                bh[ks].u[0] = t0.x; bh[ks].u[1] = t0.y;
                bh[ks].u[2] = t1.x; bh[ks].u[3] = t1.y;
                uint2 s0 = *(const uint2*)&xbl[rb + c0];
                uint2 s1 = *(const uint2*)&xbl[rb + c1];
                bl[ks].u[0] = s0.x; bl[ks].u[1] = s0.y;
                bl[ks].u[2] = s1.x; bl[ks].u[3] = s1.y;
            }
            #pragma unroll
            for (int mi = 0; mi < 4; ++mi)
                #pragma unroll
                for (int ks = 0; ks < 2; ++ks) {
                    a1[mi][ni] = MFMA(wh[mi][ks].v, bh[ks].v, a1[mi][ni]);
                    a1[mi][ni] = MFMA(wh[mi][ks].v, bl[ks].v, a1[mi][ni]);
                    a1[mi][ni] = MFMA(wl[mi][ks].v, bh[ks].v, a1[mi][ni]);
                }
        }

        // epilogue: exp on K-waves, pack bf16 into kvb
        const bool isK = og < 2;
        #pragma unroll
        for (int mi = 0; mi < 4; ++mi)
            #pragma unroll
            for (int ni = 0; ni < 4; ++ni)
                #pragma unroll
                for (int j = 0; j < 4; ++j) {
                    float v = a1[mi][ni][j];
                    if (isK) v = __expf(v);
                    const int row = og * 64 + mi * 16 + q * 4 + j;
                    const int px  = ni * 16 + l15;
                    const int pp  = (px >> 1) ^ (((row >> 2) & 7) << 2);
                    ((u16*)kvb)[(row * 32 + pp) * 2 + (px & 1)] = (u16)f2bf(v);
                }
        __syncthreads();                         // kvb ready

        // phase 2: ctx(32x32) += EK x V^T, rowsum via B=ones
        const int hb0 = og * 32;
        const int hb1 = 128 + og * 32;
        #pragma unroll
        for (int ksp = 0; ksp < 2; ++ksp) {
            FragU ak[2], av[2];
            #pragma unroll
            for (int mi = 0; mi < 2; ++mi) {
                {
                    const int row = hb0 + mi * 16 + l15;
                    const int Xr = ((row >> 2) & 7) << 2;
                    const int p0 = (ksp * 16 + 2 * q) ^ Xr;
                    const int p1 = (ksp * 16 + 2 * q + 8) ^ Xr;
                    uint2 t0 = *(const uint2*)&kvb[row * 32 + p0];
                    uint2 t1 = *(const uint2*)&kvb[row * 32 + p1];
                    ak[mi].u[0] = t0.x; ak[mi].u[1] = t0.y;
                    ak[mi].u[2] = t1.x; ak[mi].u[3] = t1.y;
                }
                {
                    const int row = hb1 + mi * 16 + l15;
                    const int Xr = ((row >> 2) & 7) << 2;
                    const int p0 = (ksp * 16 + 2 * q) ^ Xr;
                    const int p1 = (ksp * 16 + 2 * q + 8) ^ Xr;
                    uint2 t0 = *(const uint2*)&kvb[row * 32 + p0];
                    uint2 t1 = *(const uint2*)&kvb[row * 32 + p1];
                    av[mi].u[0] = t0.x; av[mi].u[1] = t0.y;
                    av[mi].u[2] = t1.x; av[mi].u[3] = t1.y;
                }
            }
            #pragma unroll
            for (int mi = 0; mi < 2; ++mi) {
                #pragma unroll
                for (int ni = 0; ni < 2; ++ni)
                    cc[mi][ni] = MFMA(ak[mi].v, av[ni].v, cc[mi][ni]);
                rsa[mi] = MFMA(ak[mi].v, ones.v, rsa[mi]);
            }
        }
    }

    // epilogue: per-block partials (or atomic replicas)
    if (usePart) {
        float* pp = part + (long)blk * PART_STRIDE;
        #pragma unroll
        for (int mi = 0; mi < 2; ++mi)
            #pragma unroll
            for (int ni = 0; ni < 2; ++ni)
                #pragma unroll
                for (int j = 0; j < 4; ++j)
                    pp[og * 1024 + (mi * 16 + q * 4 + j) * 32 + ni * 16 + l15] = cc[mi][ni][j];
        if (l15 == 0) {
            #pragma unroll
            for (int mi = 0; mi < 2; ++mi)
                #pragma unroll
                for (int j = 0; j < 4; ++j)
                    pp[4096 + og * 32 + mi * 16 + q * 4 + j] = rsa[mi][j];
        }
    } else {
        float* pp = part + (long)(b * R + (blk % R)) * PART_STRIDE;
        #pragma unroll
        for (int mi = 0; mi < 2; ++mi)
            #pragma unroll
            for (int ni = 0; ni < 2; ++ni)
                #pragma unroll
                for (int j = 0; j < 4; ++j)
                    atomicAdd(&pp[og * 1024 + (mi * 16 + q * 4 + j) * 32 + ni * 16 + l15], cc[mi][ni][j]);
        if (l15 == 0) {
            #pragma unroll
            for (int mi = 0; mi < 2; ++mi)
                #pragma unroll
                for (int j = 0; j < 4; ++j)
                    atomicAdd(&pp[4096 + og * 32 + mi * 16 + q * 4 + j], rsa[mi][j]);
        }
    }
}

// ---------------- K1b: reduce partials -> ctx, rsum (atomic, sliced) -----
__global__ __launch_bounds__(128)
void k1b_reduce(float* __restrict__ ws, int PB) {
    const int S = 8;
    const int chunk = blockIdx.x % 33;
    const int rem   = blockIdx.x / 33;
    const int b     = rem & 1;
    const int slice = rem >> 1;
    const int j = chunk * 128 + threadIdx.x;       // [0, 4224)
    const int PBh = PB >> 1;
    const float* part = ws + WS_PART;
    float s = 0.f;
    for (int pi = b * PBh + slice; pi < (b + 1) * PBh; pi += S)
        s += part[(long)pi * PART_STRIDE + j];
    float* dst = (j < 4096) ? (ws + WS_CTX + b * 4096 + j)
                            : (ws + WS_RS + b * 128 + (j - 4096));
    atomicAdd(dst, s);
}

// ---------------- K2: ATb[up][o] = packed bf16 pair of A^T ---------------
// A[hc][o] = sum_d w_out[o, hh*32+d] * ctx[hh][c][d] / rsum[hc]
__global__ __launch_bounds__(256)
void k2_prepA(const float* __restrict__ wout, float* __restrict__ ws) {
    __shared__ float wo[64 * 129];
    __shared__ float ct[4096];
    __shared__ float rsum[128];
    const int b   = blockIdx.x;
    const int tid = threadIdx.x;
    for (int i = tid; i < 8192; i += 256) wo[(i >> 7) * 129 + (i & 127)] = wout[i];
    for (int i = tid; i < 4096; i += 256) ct[i] = ws[WS_CTX + b * 4096 + i];
    if (tid < 128) rsum[tid] = ws[WS_RS + b * 128 + tid];
    __syncthreads();
    u32* atb = (u32*)ws + WS_ATB + b * 4096;
    const int o  = tid & 63;
    const int ug = tid >> 6;
    for (int i = 0; i < 16; ++i) {
        const int up = ug * 16 + i;
        const int hc0 = 2 * up, hc1 = 2 * up + 1;
        const int hh = hc0 >> 5;
        const int c0 = hc0 & 31, c1 = hc1 & 31;
        float s0 = 0.f, s1 = 0.f;
        #pragma unroll
        for (int d = 0; d < 32; ++d) {
            const float w = wo[o * 129 + hh * 32 + d];
            s0 = fmaf(w, ct[hh * 1024 + c0 * 32 + d], s0);
            s1 = fmaf(w, ct[hh * 1024 + c1 * 32 + d], s1);
        }
        atb[up * 64 + o] = pk2(s0 / rsum[hc0], s1 / rsum[hc1]);
    }
}

// ---------------- K3: q GEMM (MFMA) + in-reg softmax + A@q (MFMA) --------
__global__ __launch_bounds__(256, 2)
void k3_out(const float* __restrict__ x, const float* __restrict__ wq,
            const float* __restrict__ bout, const float* __restrict__ wsf,
            float* __restrict__ out) {
    __shared__ float xt[64 * 64];      // 16 KB
    __shared__ u32   xbh[64 * 32];     // 8 KB
    __shared__ u32   xbl[64 * 32];     // 8 KB
    __shared__ u16   qb[64 * 128];     // [px][hc] bf16, swizzled, 16 KB
    const int blk  = blockIdx.x;
    const int b    = blk / NTILES;
    const int tile = blk % NTILES;
    const long i0  = (long)tile * 64;
    const int p    = threadIdx.x & 63;
    const int og   = __builtin_amdgcn_readfirstlane(threadIdx.x >> 6);
    const int q    = p >> 4;
    const int l15  = p & 15;
    const int yv   = (p & 7) << 2;
    const float* xg = x + (long)b * 64 * NPIX;
    const int srow = p >> 4, scol = (p & 15) << 2;

    {   // stage x
        #pragma unroll
        for (int i = 0; i < 4; ++i) {
            const int r0 = og * 16 + i * 4;
            gll16(xg + (long)(r0 + srow) * NPIX + i0 + scol, &xt[r0 * 64]);
        }
    }

    // W frags: q rows og*32..+32, split
    FragU wh[2][2], wl[2][2];
    #pragma unroll
    for (int mi = 0; mi < 2; ++mi)
        #pragma unroll
        for (int ks = 0; ks < 2; ++ks) {
            const int row = og * 32 + mi * 16 + l15;
            const float* wp = wq + row * 64 + ks * 32 + q * 4;
            float4 f0 = *(const float4*)wp;
            float4 f1 = *(const float4*)(wp + 16);
            split2(f0.x, f0.y, wh[mi][ks].u[0], wl[mi][ks].u[0]);
            split2(f0.z, f0.w, wh[mi][ks].u[1], wl[mi][ks].u[1]);
            split2(f1.x, f1.y, wh[mi][ks].u[2], wl[mi][ks].u[2]);
            split2(f1.z, f1.w, wh[mi][ks].u[3], wl[mi][ks].u[3]);
        }

    // ATb frags (per-b matrix, packed bf16 pairs)
    const u32* atb = (const u32*)wsf + WS_ATB + b * 4096;
    FragU af[4];
    #pragma unroll
    for (int ks = 0; ks < 4; ++ks) {
        const int up0 = ks * 16 + 2 * q;
        const int o   = og * 16 + l15;
        af[ks].u[0] = atb[(up0)     * 64 + o];
        af[ks].u[1] = atb[(up0 + 1) * 64 + o];
        af[ks].u[2] = atb[(up0 + 8) * 64 + o];
        af[ks].u[3] = atb[(up0 + 9) * 64 + o];
    }
    const float4 bias = *(const float4*)&bout[og * 16 + q * 4];

    asm volatile("s_waitcnt vmcnt(0)" ::: "memory");
    __syncthreads();

    // transpose-pack
    {
        const int px = threadIdx.x & 63;
        const int cg = threadIdx.x >> 6;
        u32 hb_[8], lb_[8];
        #pragma unroll
        for (int w = 0; w < 8; ++w) {
            const int c = (cg * 8 + w) * 2;
            split2(xt[c * 64 + px], xt[(c + 1) * 64 + px], hb_[w], lb_[w]);
        }
        const int yy = (px & 7) << 2;
        const int sA = (cg * 8) ^ yy;
        const int sB = (cg * 8 + 4) ^ yy;
        *(uint4*)&xbh[px * 32 + sA] = make_uint4(hb_[0], hb_[1], hb_[2], hb_[3]);
        *(uint4*)&xbh[px * 32 + sB] = make_uint4(hb_[4], hb_[5], hb_[6], hb_[7]);
        *(uint4*)&xbl[px * 32 + sA] = make_uint4(lb_[0], lb_[1], lb_[2], lb_[3]);
        *(uint4*)&xbl[px * 32 + sB] = make_uint4(lb_[4], lb_[5], lb_[6], lb_[7]);
    }
    __syncthreads();

    // phase 1: q = W x (split bf16)
    f32x4 a1[2][4];
    #pragma unroll
    for (int mi = 0; mi < 2; ++mi)
        #pragma unroll
        for (int ni = 0; ni < 4; ++ni) a1[mi][ni] = (f32x4)0.f;
    #pragma unroll
    for (int ni = 0; ni < 4; ++ni) {
        const int rb = (ni * 16 + l15) * 32;
        FragU bh[2], bl[2];
        #pragma unroll
        for (int ks = 0; ks < 2; ++ks) {
            const int c0 = (ks * 16 + 2 * q) ^ yv;
            const int c1 = (ks * 16 + 2 * q + 8) ^ yv;
            uint2 t0 = *(const uint2*)&xbh[rb + c0];
            uint2 t1 = *(const uint2*)&xbh[rb + c1];
            bh[ks].u[0] = t0.x; bh[ks].u[1] = t0.y;
            bh[ks].u[2] = t1.x; bh[ks].u[3] = t1.y;
            uint2 s0 = *(const uint2*)&xbl[rb + c0];
            uint2 s1 = *(const uint2*)&xbl[rb + c1];
            bl[ks].u[0] = s0.x; bl[ks].u[1] = s0.y;
            bl[ks].u[2] = s1.x; bl[ks].u[3] = s1.y;
        }
        #pragma unroll
        for (int mi = 0; mi < 2; ++mi)
            #pragma unroll
            for (int ks = 0; ks < 2; ++ks) {
                a1[mi][ni] = MFMA(wh[mi][ks].v, bh[ks].v, a1[mi][ni]);
                a1[mi][ni] = MFMA(wh[mi][ks].v, bl[ks].v, a1[mi][ni]);
                a1[mi][ni] = MFMA(wl[mi][ks].v, bh[ks].v, a1[mi][ni]);
            }
    }

    // phase 2: in-register softmax over head og's 32 rows, per px column
    #pragma unroll
    for (int ni = 0; ni < 4; ++ni) {
        float mx = a1[0][ni][0];
        #pragma unroll
        for (int mi = 0; mi < 2; ++mi)
            #pragma unroll
            for (int j = 0; j < 4; ++j) mx = fmaxf(mx, a1[mi][ni][j]);
        mx = fmaxf(mx, __shfl_xor(mx, 16));
        mx = fmaxf(mx, __shfl_xor(mx, 32));
        float e[2][4];
        float sm = 0.f;
        #pragma unroll
        for (int mi = 0; mi < 2; ++mi)
            #pragma unroll
            for (int j = 0; j < 4; ++j) {
                e[mi][j] = __expf(a1[mi][ni][j] - mx);
                sm += e[mi][j];
            }
        sm += __shfl_xor(sm, 16);
        sm += __shfl_xor(sm, 32);
        const float inv = 1.0f / sm;
        const int px = ni * 16 + l15;
        #pragma unroll
        for (int mi = 0; mi < 2; ++mi)
            #pragma unroll
            for (int j = 0; j < 4; ++j) {
                const int hc = og * 32 + mi * 16 + q * 4 + j;
                qb[px * 128 + (hc ^ ((px & 7) << 3))] = (u16)f2bf(e[mi][j] * inv);
            }
    }
    __syncthreads();

    // phase 3: out = A^T qsm + bias
    f32x4 a3[4];
    #pragma unroll
    for (int ni = 0; ni < 4; ++ni) a3[ni] = (f32x4)0.f;
    const u32* qb32 = (const u32*)qb;
    #pragma unroll
    for (int ni = 0; ni < 4; ++ni) {
        const int px = ni * 16 + l15;
        const int rb = px * 64;
        #pragma unroll
        for (int ks = 0; ks < 4; ++ks) {
            const int c0 = (ks * 16 + 2 * q) ^ yv;
            const int c1 = (ks * 16 + 2 * q + 8) ^ yv;
            uint2 t0 = *(const uint2*)&qb32[rb + c0];
            uint2 t1 = *(const uint2*)&qb32[rb + c1];
            FragU bq;
            bq.u[0] = t0.x; bq.u[1] = t0.y; bq.u[2] = t1.x; bq.u[3] = t1.y;
            a3[ni] = MFMA(af[ks].v, bq.v, a3[ni]);
        }
    }
    #pragma unroll
    for (int ni = 0; ni < 4; ++ni)
        #pragma unroll
        for (int j = 0; j < 4; ++j)
            out[((long)b * 64 + og * 16 + q * 4 + j) * NPIX + i0 + ni * 16 + l15] =
                a3[ni][j] + bias[j];
}

extern "C" void kernel_launch(void* const* d_in, const int* in_sizes, int n_in,
                              void* d_out, int out_size, void* d_ws, size_t ws_size,
                              hipStream_t stream) {
    (void)in_sizes; (void)n_in; (void)out_size;
    const float* x     = (const float*)d_in[0];
    const float* w_qkv = (const float*)d_in[1];
    const float* w_out = (const float*)d_in[2];
    const float* b_out = (const float*)d_in[3];
    float* out = (float*)d_out;
    float* ws  = (float*)d_ws;

    const size_t need_part = ((size_t)WS_PART + (size_t)K1_BLOCKS * PART_STRIDE) * 4;
    const int usePart = (ws_size >= need_part) ? 1 : 0;
    int R = 8;
    const size_t need_r8 = ((size_t)WS_PART + (size_t)2 * 8 * PART_STRIDE) * 4;
    if (!usePart && ws_size < need_r8) R = 1;
    const int PB = usePart ? K1_BLOCKS : 2 * R;
    float* part = ws + WS_PART;

    if (!usePart)
        hipMemsetAsync(part, 0, (size_t)PB * PART_STRIDE * 4, stream);
    hipLaunchKernelGGL(k1_ctx, dim3(K1_BLOCKS), dim3(256), 0, stream,
                       x, w_qkv, part, usePart, R);
    hipMemsetAsync(ws + WS_CTX, 0, (size_t)(2 * PART_STRIDE) * 4, stream);
    hipLaunchKernelGGL(k1b_reduce, dim3(528), dim3(128), 0, stream, ws, PB);
    hipLaunchKernelGGL(k2_prepA, dim3(2), dim3(256), 0, stream, w_out, ws);
    hipLaunchKernelGGL(k3_out, dim3(2 * NTILES), dim3(256), 0, stream,
                       x, w_qkv, b_out, ws, out);
}